// Round 1
// baseline (36.819 us; speedup 1.0000x reference)
//
#include <hip/hip_runtime.h>

#define N 6144
#define NTYPE 4
#define EPS_MIN 1.0f
#define EPS_MAX 5.0f
#define ALPHA 2.8f
#define R_CUTOFF 2.0f
#define R_ONSET 1.7f

constexpr int TILE = 256;
constexpr int NBLK = N / TILE;          // 24
constexpr int NPART = NBLK * NBLK;      // 576 partial sums

// smooth-cutoff constants (compile-time, double -> float)
constexpr float RC2 = R_CUTOFF * R_CUTOFF;              // 4.0
constexpr float RO2 = R_ONSET * R_ONSET;                // 2.89
constexpr float INV_DENOM = 1.0f / ((RC2 - RO2) * (RC2 - RO2) * (RC2 - RO2));

__device__ __forceinline__ float block_reduce_256(float v) {
    __shared__ float ws[4];
    #pragma unroll
    for (int off = 32; off > 0; off >>= 1) v += __shfl_down(v, off);
    const int lane = threadIdx.x & 63;
    const int wid  = threadIdx.x >> 6;
    if (lane == 0) ws[wid] = v;
    __syncthreads();
    if (wid == 0) {
        v = (lane < 4) ? ws[lane] : 0.0f;
        #pragma unroll
        for (int off = 2; off > 0; off >>= 1) v += __shfl_down(v, off);
    }
    return v;  // valid in thread 0
}

// Per-particle derived data loader: (x,y,z,radius) and (s, c_last, type_bits, 0)
__device__ __forceinline__ void load_particle(int idx,
                                              const float* __restrict__ pos,
                                              const float* __restrict__ celltype,
                                              const float* __restrict__ cadherin,
                                              const float* __restrict__ radius,
                                              float4& a, float4& b) {
    const float x = pos[idx * 3 + 0];
    const float y = pos[idx * 3 + 1];
    const float z = pos[idx * 3 + 2];
    const float r = radius[idx];
    float s = 0.0f;
    int   t = 0;
    float best = -1.0f;
    #pragma unroll
    for (int k = 0; k < NTYPE; ++k) {
        const float c = celltype[idx * NTYPE + k];
        s += c * cadherin[idx * (NTYPE + 1) + k];
        if (c > best) { best = c; t = k; }
    }
    const float clast = cadherin[idx * (NTYPE + 1) + NTYPE];
    a = make_float4(x, y, z, r);
    b = make_float4(s, clast, __int_as_float(t), 0.0f);
}

__global__ void __launch_bounds__(TILE)
pair_tile_kernel(const float* __restrict__ pos,
                 const float* __restrict__ celltype,
                 const float* __restrict__ cadherin,
                 const float* __restrict__ radius,
                 float* __restrict__ partial) {
    __shared__ float4 sA[TILE];
    __shared__ float4 sB[TILE];

    const int ib = blockIdx.x;
    const int jb = blockIdx.y;
    const int i  = ib * TILE + threadIdx.x;
    const int jg0 = jb * TILE;

    // Stage the j-tile (each thread prepares one j particle)
    {
        float4 a, b;
        load_particle(jg0 + (int)threadIdx.x, pos, celltype, cadherin, radius, a, b);
        sA[threadIdx.x] = a;
        sB[threadIdx.x] = b;
    }
    // This thread's i particle
    float4 ai, bi;
    load_particle(i, pos, celltype, cadherin, radius, ai, bi);
    const int   ti = __float_as_int(bi.z);
    const float si = bi.x;

    __syncthreads();

    float acc = 0.0f;
    #pragma unroll 4
    for (int jj = 0; jj < TILE; ++jj) {
        const int j = jg0 + jj;
        if (j == i) continue;                       // exclude self-interaction
        const float4 aj = sA[jj];
        const float dx = ai.x - aj.x;
        const float dy = ai.y - aj.y;
        const float dz = ai.z - aj.z;
        const float dr2 = dx * dx + dy * dy + dz * dz;
        // r >= R_CUTOFF contributes exactly 0; dr2 == 0 maps to r = 1 (safe sqrt) which IS < cutoff
        if (dr2 < RC2) {
            const float r = (dr2 > 0.0f) ? sqrtf(dr2) : 1.0f;
            const float4 bj = sB[jj];
            const float sigma = ai.w + aj.w;
            const float e = expf(-ALPHA * (r - sigma));
            const int   tj = __float_as_int(bj.z);
            float eps = (ti == tj) ? (si + bj.x) : (2.0f * bj.y);
            eps = EPS_MAX * eps + EPS_MIN;
            float cut;
            if (r < R_ONSET) {
                cut = 1.0f;
            } else {
                const float r2 = r * r;
                const float d  = RC2 - r2;
                cut = d * d * (RC2 + 2.0f * r2 - 3.0f * RO2) * INV_DENOM;
            }
            acc += eps * (e * e - 2.0f * e) * cut;
        }
    }

    const float bsum = block_reduce_256(acc);
    if (threadIdx.x == 0) partial[jb * NBLK + ib] = bsum;
}

__global__ void __launch_bounds__(256)
final_reduce_kernel(const float* __restrict__ partial, float* __restrict__ out) {
    float acc = 0.0f;
    for (int k = threadIdx.x; k < NPART; k += 256) acc += partial[k];
    const float total = block_reduce_256(acc);
    if (threadIdx.x == 0) out[0] = 0.5f * total;
}

extern "C" void kernel_launch(void* const* d_in, const int* in_sizes, int n_in,
                              void* d_out, int out_size, void* d_ws, size_t ws_size,
                              hipStream_t stream) {
    const float* pos      = (const float*)d_in[0];
    const float* celltype = (const float*)d_in[1];
    const float* cadherin = (const float*)d_in[2];
    const float* radius   = (const float*)d_in[3];
    float* out     = (float*)d_out;
    float* partial = (float*)d_ws;   // NPART floats

    dim3 grid(NBLK, NBLK);
    pair_tile_kernel<<<grid, TILE, 0, stream>>>(pos, celltype, cadherin, radius, partial);
    final_reduce_kernel<<<1, 256, 0, stream>>>(partial, out);
}